// Round 3
// baseline (163.047 us; speedup 1.0000x reference)
//
#include <hip/hip_runtime.h>

#define HW 16384
#define C 128

typedef __attribute__((ext_vector_type(8))) short short8;
typedef __attribute__((ext_vector_type(4))) float f32x4;
typedef __attribute__((ext_vector_type(2))) float f32x2;
typedef __attribute__((ext_vector_type(16))) int v16i;

__device__ __forceinline__ unsigned short f2bf(float f) {
  union { float f; unsigned u; } v; v.f = f;
  return (unsigned short)((v.u + 0x7fffu + ((v.u >> 16) & 1u)) >> 16);
}
#if __has_builtin(__builtin_amdgcn_cvt_pk_bf16_f32)
typedef __attribute__((ext_vector_type(2))) __bf16 bf16x2;
__device__ __forceinline__ unsigned pk2(float a, float b) {   // HW RNE pack
  union { bf16x2 v; unsigned u; } cv;
  cv.v = __builtin_amdgcn_cvt_pk_bf16_f32(a, b);
  return cv.u;
}
#else
__device__ __forceinline__ unsigned pk2(float a, float b) {   // SW RNE pack
  return (unsigned)f2bf(a) | ((unsigned)f2bf(b) << 16);
}
#endif
__device__ __forceinline__ unsigned short f2bf1(float a) {
  return (unsigned short)(pk2(a, a) & 0xffffu);
}
__device__ __forceinline__ float bflo(unsigned w) {
  union { unsigned u; float f; } v; v.u = w << 16; return v.f;
}
__device__ __forceinline__ float bfhi(unsigned w) {
  union { unsigned u; float f; } v; v.u = w & 0xffff0000u; return v.f;
}
__device__ __forceinline__ float asf(int u) {
  union { int u; float f; } v; v.u = u; return v.f;
}

// ---------------- Kernel 0: precompute Mt = C^-0.5 * Wk^T Wq, P = Wproj @ Wv,
// both stored bf16 with the LDS XOR swizzle pre-applied, plus bilinear pw/pi.
__global__ __launch_bounds__(128) void k_prep(const float* __restrict__ w_qkv,
                                              const float* __restrict__ w_proj,
                                              const float* __restrict__ delta,
                                              unsigned short* __restrict__ Mt,
                                              unsigned short* __restrict__ Pm,
                                              float* __restrict__ pw,
                                              int* __restrict__ pi) {
  const int bid = blockIdx.x;
  const int t = threadIdx.x;
  if (bid == 256) {
    if (t < 8) {
      float s0 = tanhf(delta[t * 2 + 0]) * 4.0f;  // col shift (x)
      float s1 = tanhf(delta[t * 2 + 1]) * 4.0f;  // row shift (y)
      float f0 = floorf(s0), f1 = floorf(s1);
      pi[2 * t + 0] = (int)f0;
      pi[2 * t + 1] = (int)f1;
      float fx = s0 - f0, fy = s1 - f1;
      pw[4 * t + 0] = (1.0f - fx) * (1.0f - fy);
      pw[4 * t + 1] = fx * (1.0f - fy);
      pw[4 * t + 2] = (1.0f - fx) * fy;
      pw[4 * t + 3] = fx * fy;
    }
    return;
  }
  const int R = bid & 127;
  float acc = 0.0f;
  if (bid < 128) {                         // Mt row R
    const float* wq = w_qkv;               // Wq[j][c]
    const float* wk = w_qkv + 128 * 128;   // Wk[j][o]
    #pragma unroll 16
    for (int j = 0; j < 128; ++j)
      acc += wk[j * 128 + R] * wq[j * 128 + t];   // wk: scalar, wq: coalesced
    acc *= 0.08838834764831845f;           // fold C^-0.5 into the logits
    Mt[R * 128 + (t ^ ((R & 7) << 3))] = f2bf1(acc);
  } else {                                 // P row R
    const float* wv = w_qkv + 2 * 128 * 128;  // Wv[j][c]
    const float* wp = w_proj + (size_t)R * 128;  // Wproj[R][j]
    #pragma unroll 16
    for (int j = 0; j < 128; ++j)
      acc += wp[j] * wv[j * 128 + t];
    Pm[R * 128 + (t ^ ((R & 7) << 3))] = f2bf1(acc);
  }
}

// ---------------- Kernel 1: q' = x * Mt GEMM + bf16 transposed copy of x -----
// 64-pixel tiles (1024 blocks, 16KB LDS). Mt fragments read straight from
// global (LLC/L1-hot, identical for all blocks). qb repacked through LDS so
// all global stores are coalesced uint4.
__global__ __launch_bounds__(256) void k_qx(const float* __restrict__ x,
                                            const unsigned short* __restrict__ Mt,
                                            unsigned short* __restrict__ qb,
                                            unsigned* __restrict__ xq) {
  __shared__ __align__(16) unsigned short Xs[64 * 128];  // 16 KB
  const int t = threadIdx.x;
  const int gpix0 = blockIdx.x * 64;
  const int b = gpix0 >> 14;
  const int hw0 = gpix0 & (HW - 1);

  // stage Xs [pix][k] bf16, xor-swizzled
  const float* xb = x + (size_t)b * C * HW + hw0;
  #pragma unroll
  for (int i = 0; i < 8; ++i) {
    int linear = i * 256 + t;
    int p = linear & 63;
    int c4 = (linear >> 6) * 4;
    float a0 = xb[(size_t)(c4 + 0) * HW + p];
    float a1 = xb[(size_t)(c4 + 1) * HW + p];
    float a2 = xb[(size_t)(c4 + 2) * HW + p];
    float a3 = xb[(size_t)(c4 + 3) * HW + p];
    int cc = c4 ^ ((p & 7) << 3);
    *(uint2*)&Xs[p * 128 + cc] = make_uint2(pk2(a0, a1), pk2(a2, a3));
  }
  __syncthreads();

  // coalesced xq emit from staged Xs: [pix][64 dwords]
  #pragma unroll
  for (int i = 0; i < 4; ++i) {
    int linear = i * 256 + t;
    int c8 = (linear & 15) * 8;
    int prow = linear >> 4;
    uint4 v = *(const uint4*)&Xs[prow * 128 + (c8 ^ ((prow & 7) << 3))];
    *(uint4*)&xq[((size_t)(gpix0 + prow)) * 64 + (c8 >> 1)] = v;
  }

  const int wave = t >> 6, lane = t & 63;
  const int wr = wave >> 1, wc = wave & 1;
  const int rsel = lane & 15, quad = lane >> 4;

  f32x4 acc[2][4];
  #pragma unroll
  for (int mi = 0; mi < 2; ++mi)
    #pragma unroll
    for (int ni = 0; ni < 4; ++ni) acc[mi][ni] = (f32x4){0.f, 0.f, 0.f, 0.f};
  #pragma unroll
  for (int ks = 0; ks < 4; ++ks) {
    const int koff = ks * 32 + quad * 8;
    short8 afr[2], bfr[4];
    #pragma unroll
    for (int mi = 0; mi < 2; ++mi) {
      int r = wr * 32 + mi * 16 + rsel;
      afr[mi] = *(const short8*)&Xs[r * 128 + (koff ^ ((r & 7) << 3))];
    }
    #pragma unroll
    for (int ni = 0; ni < 4; ++ni) {
      int r = wc * 64 + ni * 16 + rsel;
      bfr[ni] = *(const short8*)&Mt[r * 128 + (koff ^ ((r & 7) << 3))];  // global, hot
    }
    #pragma unroll
    for (int mi = 0; mi < 2; ++mi)
      #pragma unroll
      for (int ni = 0; ni < 4; ++ni)
        acc[mi][ni] = __builtin_amdgcn_mfma_f32_16x16x32_bf16(afr[mi], bfr[ni], acc[mi][ni], 0, 0, 0);
  }
  __syncthreads();   // all Xs reads done; reuse as q-tile
  #pragma unroll
  for (int mi = 0; mi < 2; ++mi)
    #pragma unroll
    for (int ni = 0; ni < 4; ++ni)
      #pragma unroll
      for (int r = 0; r < 4; ++r) {
        int p = wr * 32 + mi * 16 + quad * 4 + r;
        int ch = wc * 64 + ni * 16 + rsel;
        Xs[p * 128 + (ch ^ ((p & 7) << 3))] = f2bf1(acc[mi][ni][r]);
      }
  __syncthreads();
  // coalesced qb store
  #pragma unroll
  for (int i = 0; i < 4; ++i) {
    int linear = i * 256 + t;
    int c8 = (linear & 15) * 8;
    int prow = linear >> 4;
    uint4 v = *(const uint4*)&Xs[prow * 128 + (c8 ^ ((prow & 7) << 3))];
    *(uint4*)(qb + (size_t)(gpix0 + prow) * C + c8) = v;
  }
}

// ---------------- Kernel 2: fused gather + attention (bf16 x-samples) --------
// One wave per pixel. Tables (psf row / pw / pi) loaded via s_load_dwordx16 —
// pure SMEM+SALU, no VMEM loads or v_readfirstlane for the uniform data.
__global__ __launch_bounds__(256) void k_attn(const unsigned short* __restrict__ qb,
                                              const unsigned* __restrict__ xq,
                                              const int* __restrict__ psf,
                                              const int* __restrict__ pwu,
                                              const int* __restrict__ pi,
                                              unsigned short* __restrict__ ao) {
  (void)pi;
  const int t = threadIdx.x;
  const int lane = t & 63;
  const int p = blockIdx.x;
  const int b = (p >> 1) & 3;                    // batch -> XCD pair
  const int j = ((p >> 3) << 1) | (p & 1);
  const int spix = __builtin_amdgcn_readfirstlane((b << 14) + (j << 2) + (t >> 6));

  const unsigned* xB = xq + (size_t)b * HW * 64;  // SGPR base

  const unsigned qp = ((const unsigned*)qb)[(size_t)spix * 64 + lane];
  const float qx = bflo(qp), qy = bfhi(qp);

  // scalar loads: w0=pw[0..15], w1=pw[16..31], tpi=pi[0..15], ps=psf row
  v16i w0, w1, tpi, ps;
  asm volatile(
      "s_load_dwordx16 %0, %4, 0\n\t"
      "s_load_dwordx16 %1, %4, 64\n\t"
      "s_load_dwordx16 %2, %4, 128\n\t"
      "s_load_dwordx16 %3, %5, 0\n\t"
      "s_waitcnt lgkmcnt(0)"
      : "=&s"(w0), "=&s"(w1), "=&s"(tpi), "=&s"(ps)
      : "s"(pwu), "s"(psf + (size_t)spix * 16));

  float dk[8];
  float2 xt[8];
  #pragma unroll
  for (int k = 0; k < 8; ++k) {
    const int x0 = ps[k * 2 + 0] + tpi[2 * k + 0];   // SALU
    const int y0 = ps[k * 2 + 1] + tpi[2 * k + 1];
    float sx = 0.f, sy = 0.f;
    #pragma unroll
    for (int cn = 0; cn < 4; ++cn) {
      const int xi = x0 + (cn & 1);
      const int yi = y0 + (cn >> 1);
      const bool valid = (xi >= 0) & (xi <= 127) & (yi >= 0) & (yi <= 127);
      const int xc = min(max(xi, 0), 127);
      const int yc = min(max(yi, 0), 127);
      const int widx = k * 4 + cn;
      const int wbits = (widx < 16) ? w0[widx & 15] : w1[widx & 15];
      const float wv = asf(valid ? wbits : 0);                       // s_cselect
      const unsigned w = xB[((size_t)((yc << 7) + xc) << 6) + lane];  // s-base + lane
      sx = fmaf(bflo(w), wv, sx);
      sy = fmaf(bfhi(w), wv, sy);
    }
    xt[k] = make_float2(sx, sy);
    dk[k] = fmaf(qx, sx, qy * sy);
  }
  #pragma unroll
  for (int off = 32; off > 0; off >>= 1) {
    #pragma unroll
    for (int k = 0; k < 8; ++k) dk[k] += __shfl_xor(dk[k], off);
  }
  float m = dk[0];
  #pragma unroll
  for (int k = 1; k < 8; ++k) m = fmaxf(m, dk[k]);
  float e[8], den = 0.0f;
  #pragma unroll
  for (int k = 0; k < 8; ++k) { e[k] = __expf(dk[k] - m); den += e[k]; }
  const float inv = 1.0f / den;
  float ox = 0, oy = 0;
  #pragma unroll
  for (int k = 0; k < 8; ++k) { float pk = e[k] * inv; ox += pk * xt[k].x; oy += pk * xt[k].y; }
  ((unsigned*)ao)[(size_t)spix * 64 + lane] = pk2(ox, oy);
}

// ---------------- Kernel 3: out = x + P @ ao  (64-pixel tiles, Pm global) ----
__global__ __launch_bounds__(256) void k_proj(const unsigned short* __restrict__ ao,
                                              const unsigned short* __restrict__ Pm,
                                              const float* __restrict__ x,
                                              float* __restrict__ out) {
  __shared__ __align__(16) unsigned short As[64 * 128];  // 16 KB
  const int t = threadIdx.x;
  const int gpix0 = blockIdx.x * 64;
  const int b = gpix0 >> 14;
  const int hw0 = gpix0 & (HW - 1);

  #pragma unroll
  for (int i = 0; i < 4; ++i) {
    int linear = i * 256 + t;
    int c8 = (linear & 15) * 8;
    int p = linear >> 4;
    uint4 v = *(const uint4*)(ao + (size_t)(gpix0 + p) * C + c8);
    *(uint4*)&As[p * 128 + (c8 ^ ((p & 7) << 3))] = v;
  }
  __syncthreads();

  const int wave = t >> 6, lane = t & 63;
  const int wr = wave >> 1, wc = wave & 1;
  const int rsel = lane & 15, quad = lane >> 4;

  f32x4 acc[4][2];
  #pragma unroll
  for (int mi = 0; mi < 4; ++mi)
    #pragma unroll
    for (int ni = 0; ni < 2; ++ni) acc[mi][ni] = (f32x4){0.f, 0.f, 0.f, 0.f};

  #pragma unroll
  for (int ks = 0; ks < 4; ++ks) {
    const int koff = ks * 32 + quad * 8;
    short8 afr[4], bfr[2];
    #pragma unroll
    for (int mi = 0; mi < 4; ++mi) {
      int r = wr * 64 + mi * 16 + rsel;
      afr[mi] = *(const short8*)&Pm[r * 128 + (koff ^ ((r & 7) << 3))];  // global, hot
    }
    #pragma unroll
    for (int ni = 0; ni < 2; ++ni) {
      int r = wc * 32 + ni * 16 + rsel;
      bfr[ni] = *(const short8*)&As[r * 128 + (koff ^ ((r & 7) << 3))];
    }
    #pragma unroll
    for (int mi = 0; mi < 4; ++mi)
      #pragma unroll
      for (int ni = 0; ni < 2; ++ni)
        acc[mi][ni] = __builtin_amdgcn_mfma_f32_16x16x32_bf16(afr[mi], bfr[ni], acc[mi][ni], 0, 0, 0);
  }

  #pragma unroll
  for (int mi = 0; mi < 4; ++mi)
    #pragma unroll
    for (int ni = 0; ni < 2; ++ni)
      #pragma unroll
      for (int r = 0; r < 4; ++r) {
        int och = wr * 64 + mi * 16 + quad * 4 + r;
        int pixl = wc * 32 + ni * 16 + rsel;
        size_t addr = ((size_t)b * C + och) * HW + hw0 + pixl;
        out[addr] = x[addr] + acc[mi][ni][r];
      }
}

extern "C" void kernel_launch(void* const* d_in, const int* in_sizes, int n_in,
                              void* d_out, int out_size, void* d_ws, size_t ws_size,
                              hipStream_t stream) {
  const float* x      = (const float*)d_in[0];
  const int*   psf    = (const int*)d_in[1];
  const float* delta  = (const float*)d_in[2];
  const float* w_qkv  = (const float*)d_in[3];
  const float* w_proj = (const float*)d_in[4];
  float* out = (float*)d_out;

  const size_t N = (size_t)4 * HW * C;                 // 8388608 elems
  unsigned short* qb = (unsigned short*)d_ws;          // 16 MB bf16 q' [pix][ch]
  unsigned short* xq = qb + N;                         // 16 MB bf16 x~ [pix][ch]
  unsigned short* ao = xq + N;                         // 16 MB bf16 out-acc
  unsigned short* Mt = ao + N;                         // 32 KB bf16 swz
  unsigned short* Pm = Mt + 16384;                     // 32 KB bf16 swz
  float* pw = (float*)(Pm + 16384);                    // 32 floats (pi follows)
  int*   pi = (int*)(pw + 32);                         // 16 ints

  k_prep<<<dim3(257), 128, 0, stream>>>(w_qkv, w_proj, delta, Mt, Pm, pw, pi);
  k_qx<<<dim3(1024), 256, 0, stream>>>(x, Mt, qb, (unsigned*)xq);
  k_attn<<<dim3(HW), 256, 0, stream>>>(qb, (const unsigned*)xq, psf, (const int*)pw, pi, ao);
  k_proj<<<dim3(1024), 256, 0, stream>>>(ao, Pm, x, out);
}

// Round 4
// 154.139 us; speedup vs baseline: 1.0578x; 1.0578x over previous
//
#include <hip/hip_runtime.h>

#define HW 16384
#define C 128

typedef __attribute__((ext_vector_type(8))) short short8;
typedef __attribute__((ext_vector_type(4))) float f32x4;
typedef __attribute__((ext_vector_type(2))) float f32x2;
typedef __attribute__((ext_vector_type(16))) int v16i;

__device__ __forceinline__ unsigned short f2bf(float f) {
  union { float f; unsigned u; } v; v.f = f;
  return (unsigned short)((v.u + 0x7fffu + ((v.u >> 16) & 1u)) >> 16);
}
#if __has_builtin(__builtin_amdgcn_cvt_pk_bf16_f32)
typedef __attribute__((ext_vector_type(2))) __bf16 bf16x2;
__device__ __forceinline__ unsigned pk2(float a, float b) {   // HW RNE pack
  union { bf16x2 v; unsigned u; } cv;
  cv.v = __builtin_amdgcn_cvt_pk_bf16_f32(a, b);
  return cv.u;
}
#else
__device__ __forceinline__ unsigned pk2(float a, float b) {   // SW RNE pack
  return (unsigned)f2bf(a) | ((unsigned)f2bf(b) << 16);
}
#endif
__device__ __forceinline__ unsigned short f2bf1(float a) {
  return (unsigned short)(pk2(a, a) & 0xffffu);
}
__device__ __forceinline__ float bflo(unsigned w) {
  union { unsigned u; float f; } v; v.u = w << 16; return v.f;
}
__device__ __forceinline__ float bfhi(unsigned w) {
  union { unsigned u; float f; } v; v.u = w & 0xffff0000u; return v.f;
}
__device__ __forceinline__ float asf(int u) {
  union { int u; float f; } v; v.u = u; return v.f;
}
__device__ __forceinline__ float bf2f(unsigned short h) {
  union { unsigned u; float f; } v; v.u = ((unsigned)h) << 16; return v.f;
}

// ---------------- Kernel 0: precompute Mt = C^-0.5 * Wk^T Wq, P = Wproj @ Wv,
// both stored bf16 with the LDS XOR swizzle pre-applied, plus bilinear pw/pi.
__global__ __launch_bounds__(128) void k_prep(const float* __restrict__ w_qkv,
                                              const float* __restrict__ w_proj,
                                              const float* __restrict__ delta,
                                              unsigned short* __restrict__ Mt,
                                              unsigned short* __restrict__ Pm,
                                              float* __restrict__ pw,
                                              int* __restrict__ pi) {
  const int bid = blockIdx.x;
  const int t = threadIdx.x;
  if (bid == 256) {
    if (t < 8) {
      float s0 = tanhf(delta[t * 2 + 0]) * 4.0f;  // col shift (x)
      float s1 = tanhf(delta[t * 2 + 1]) * 4.0f;  // row shift (y)
      float f0 = floorf(s0), f1 = floorf(s1);
      pi[2 * t + 0] = (int)f0;
      pi[2 * t + 1] = (int)f1;
      float fx = s0 - f0, fy = s1 - f1;
      pw[4 * t + 0] = (1.0f - fx) * (1.0f - fy);
      pw[4 * t + 1] = fx * (1.0f - fy);
      pw[4 * t + 2] = (1.0f - fx) * fy;
      pw[4 * t + 3] = fx * fy;
    }
    return;
  }
  const int R = bid & 127;
  float acc = 0.0f;
  if (bid < 128) {                         // Mt row R
    const float* wq = w_qkv;               // Wq[j][c]
    const float* wk = w_qkv + 128 * 128;   // Wk[j][o]
    #pragma unroll 16
    for (int j = 0; j < 128; ++j)
      acc += wk[j * 128 + R] * wq[j * 128 + t];   // wk: scalar, wq: coalesced
    acc *= 0.08838834764831845f;           // fold C^-0.5 into the logits
    Mt[R * 128 + (t ^ ((R & 7) << 3))] = f2bf1(acc);
  } else {                                 // P row R
    const float* wv = w_qkv + 2 * 128 * 128;  // Wv[j][c]
    const float* wp = w_proj + (size_t)R * 128;  // Wproj[R][j]
    #pragma unroll 16
    for (int j = 0; j < 128; ++j)
      acc += wp[j] * wv[j * 128 + t];
    Pm[R * 128 + (t ^ ((R & 7) << 3))] = f2bf1(acc);
  }
}

// ---------------- Kernel 1: q' = x * Mt GEMM + bf16 transposed copy of x -----
// 128-pixel tiles, Ws staged in LDS (R2 structure, measured best). q' repacked
// through the freed Xs buffer so qb stores are coalesced uint4 (not 2B scatter).
__global__ __launch_bounds__(256) void k_qx(const float* __restrict__ x,
                                            const unsigned short* __restrict__ Mt,
                                            unsigned short* __restrict__ qb,
                                            unsigned* __restrict__ xq) {
  __shared__ __align__(16) unsigned char smem[65536];
  unsigned short* Xs = (unsigned short*)smem;            // [pix][k] 32 KB
  unsigned short* Ws = (unsigned short*)(smem + 32768);  // [och][k] 32 KB
  const int t = threadIdx.x;
  const int gpix0 = blockIdx.x * 128;
  const int b = gpix0 >> 14;
  const int hw0 = gpix0 & (HW - 1);

  // stage Xs [pix][k] bf16, xor-swizzled
  const float* xb = x + (size_t)b * C * HW + hw0;
  #pragma unroll
  for (int i = 0; i < 16; ++i) {
    int linear = i * 256 + t;
    int p = linear & 127;
    int c4 = (linear >> 7) * 4;
    float a0 = xb[(size_t)(c4 + 0) * HW + p];
    float a1 = xb[(size_t)(c4 + 1) * HW + p];
    float a2 = xb[(size_t)(c4 + 2) * HW + p];
    float a3 = xb[(size_t)(c4 + 3) * HW + p];
    int cc = c4 ^ ((p & 7) << 3);
    *(uint2*)&Xs[p * 128 + cc] = make_uint2(pk2(a0, a1), pk2(a2, a3));
  }
  // stage Ws: pre-swizzled bf16 Mt, straight 32 KB copy
  #pragma unroll
  for (int i = 0; i < 8; ++i)
    ((uint4*)Ws)[i * 256 + t] = ((const uint4*)Mt)[i * 256 + t];
  __syncthreads();

  // coalesced xq emit from staged Xs: [pix][64 dwords]
  #pragma unroll
  for (int i = 0; i < 8; ++i) {
    int linear = i * 256 + t;
    int c8 = (linear & 15) * 8;
    int prow = linear >> 4;
    uint4 v = *(const uint4*)&Xs[prow * 128 + (c8 ^ ((prow & 7) << 3))];
    *(uint4*)&xq[((size_t)(gpix0 + prow)) * 64 + (c8 >> 1)] = v;
  }

  const int wave = t >> 6, lane = t & 63;
  const int wr = wave >> 1, wc = wave & 1;
  const int rsel = lane & 15, quad = lane >> 4;

  f32x4 acc[4][4];
  #pragma unroll
  for (int mi = 0; mi < 4; ++mi)
    #pragma unroll
    for (int ni = 0; ni < 4; ++ni) acc[mi][ni] = (f32x4){0.f, 0.f, 0.f, 0.f};
  #pragma unroll
  for (int ks = 0; ks < 4; ++ks) {
    const int koff = ks * 32 + quad * 8;
    short8 afr[4], bfr[4];
    #pragma unroll
    for (int mi = 0; mi < 4; ++mi) {
      int r = wr * 64 + mi * 16 + rsel;
      afr[mi] = *(const short8*)&Xs[r * 128 + (koff ^ ((r & 7) << 3))];
    }
    #pragma unroll
    for (int ni = 0; ni < 4; ++ni) {
      int r = wc * 64 + ni * 16 + rsel;
      bfr[ni] = *(const short8*)&Ws[r * 128 + (koff ^ ((r & 7) << 3))];
    }
    #pragma unroll
    for (int mi = 0; mi < 4; ++mi)
      #pragma unroll
      for (int ni = 0; ni < 4; ++ni)
        acc[mi][ni] = __builtin_amdgcn_mfma_f32_16x16x32_bf16(afr[mi], bfr[ni], acc[mi][ni], 0, 0, 0);
  }
  __syncthreads();   // all Xs/Ws reads done; reuse Xs as q'-tile
  #pragma unroll
  for (int mi = 0; mi < 4; ++mi)
    #pragma unroll
    for (int ni = 0; ni < 4; ++ni)
      #pragma unroll
      for (int r = 0; r < 4; ++r) {
        int p = wr * 64 + mi * 16 + quad * 4 + r;
        int ch = wc * 64 + ni * 16 + rsel;
        Xs[p * 128 + (ch ^ ((p & 7) << 3))] = f2bf1(acc[mi][ni][r]);
      }
  __syncthreads();
  // coalesced qb store
  #pragma unroll
  for (int i = 0; i < 8; ++i) {
    int linear = i * 256 + t;
    int c8 = (linear & 15) * 8;
    int prow = linear >> 4;
    uint4 v = *(const uint4*)&Xs[prow * 128 + (c8 ^ ((prow & 7) << 3))];
    *(uint4*)(qb + (size_t)(gpix0 + prow) * C + c8) = v;
  }
}

// ---------------- Kernel 2: fused gather + attention (bf16 x-samples) --------
// One wave per pixel. Tables via s_load (SALU); all 32 corner gathers issued
// into a register array FIRST (no vmcnt serialization from reg starvation),
// then the weighted accumulation runs over the in-flight results.
__global__ __launch_bounds__(256) void k_attn(const unsigned short* __restrict__ qb,
                                              const unsigned* __restrict__ xq,
                                              const int* __restrict__ psf,
                                              const int* __restrict__ pwu,
                                              const int* __restrict__ pi,
                                              unsigned short* __restrict__ ao) {
  (void)pi;
  const int t = threadIdx.x;
  const int lane = t & 63;
  const int p = blockIdx.x;
  const int b = (p >> 1) & 3;                    // batch -> XCD pair
  const int j = ((p >> 3) << 1) | (p & 1);
  const int spix = __builtin_amdgcn_readfirstlane((b << 14) + (j << 2) + (t >> 6));

  const unsigned* xB = xq + (size_t)b * HW * 64;  // SGPR base

  const unsigned qp = ((const unsigned*)qb)[(size_t)spix * 64 + lane];
  const float qx = bflo(qp), qy = bfhi(qp);

  // scalar loads: w0=pw[0..15], w1=pw[16..31], tpi=pi[0..15], ps=psf row
  v16i w0, w1, tpi, ps;
  asm volatile(
      "s_load_dwordx16 %0, %4, 0\n\t"
      "s_load_dwordx16 %1, %4, 64\n\t"
      "s_load_dwordx16 %2, %4, 128\n\t"
      "s_load_dwordx16 %3, %5, 0\n\t"
      "s_waitcnt lgkmcnt(0)"
      : "=&s"(w0), "=&s"(w1), "=&s"(tpi), "=&s"(ps)
      : "s"(pwu), "s"(psf + (size_t)spix * 16));

  // ---- issue ALL 32 corner loads (independent, stay in flight) ----
  unsigned wreg[32];
  #pragma unroll
  for (int k = 0; k < 8; ++k) {
    const int x0 = ps[k * 2 + 0] + tpi[2 * k + 0];   // SALU
    const int y0 = ps[k * 2 + 1] + tpi[2 * k + 1];
    #pragma unroll
    for (int cn = 0; cn < 4; ++cn) {
      const int xc = min(max(x0 + (cn & 1), 0), 127);
      const int yc = min(max(y0 + (cn >> 1), 0), 127);
      wreg[k * 4 + cn] = xB[((size_t)((yc << 7) + xc) << 6) + lane];
    }
  }

  // ---- weighted accumulation ----
  float dk[8];
  float2 xt[8];
  #pragma unroll
  for (int k = 0; k < 8; ++k) {
    const int x0 = ps[k * 2 + 0] + tpi[2 * k + 0];
    const int y0 = ps[k * 2 + 1] + tpi[2 * k + 1];
    float sx = 0.f, sy = 0.f;
    #pragma unroll
    for (int cn = 0; cn < 4; ++cn) {
      const int xi = x0 + (cn & 1);
      const int yi = y0 + (cn >> 1);
      const bool valid = (xi >= 0) & (xi <= 127) & (yi >= 0) & (yi <= 127);
      const int widx = k * 4 + cn;
      const int wbits = (widx < 16) ? w0[widx & 15] : w1[widx & 15];
      const float wv = asf(valid ? wbits : 0);          // s_cselect
      const unsigned w = wreg[widx];
      sx = fmaf(bflo(w), wv, sx);
      sy = fmaf(bfhi(w), wv, sy);
    }
    xt[k] = make_float2(sx, sy);
    dk[k] = fmaf(qx, sx, qy * sy);
  }
  #pragma unroll
  for (int off = 32; off > 0; off >>= 1) {
    #pragma unroll
    for (int k = 0; k < 8; ++k) dk[k] += __shfl_xor(dk[k], off);
  }
  float m = dk[0];
  #pragma unroll
  for (int k = 1; k < 8; ++k) m = fmaxf(m, dk[k]);
  float den = 0.0f;
  #pragma unroll
  for (int k = 0; k < 8; ++k) { dk[k] = __expf(dk[k] - m); den += dk[k]; }
  const float inv = 1.0f / den;
  float ox = 0, oy = 0;
  #pragma unroll
  for (int k = 0; k < 8; ++k) { float pk = dk[k] * inv; ox += pk * xt[k].x; oy += pk * xt[k].y; }
  ((unsigned*)ao)[(size_t)spix * 64 + lane] = pk2(ox, oy);
}

// ---------------- Kernel 3: out = bf16(x) + P @ ao  (128-tile, Ws in LDS) ----
// Residual read from the 16MB bf16 xq copy (re-staged through the freed As
// buffer after MFMA) instead of the 128MB fp32 x.
__global__ __launch_bounds__(256) void k_proj(const unsigned short* __restrict__ ao,
                                              const unsigned short* __restrict__ Pm,
                                              const unsigned short* __restrict__ xqh,
                                              float* __restrict__ out) {
  __shared__ __align__(16) unsigned short As[128 * 128];
  __shared__ __align__(16) unsigned short Ws[128 * 128];
  const int t = threadIdx.x;
  const int gpix0 = blockIdx.x * 128;
  const int b = gpix0 >> 14;
  const int hw0 = gpix0 & (HW - 1);

  #pragma unroll
  for (int i = 0; i < 8; ++i) {
    int linear = i * 256 + t;
    int c8 = (linear & 15) * 8;
    int p = linear >> 4;
    uint4 v = *(const uint4*)(ao + (size_t)(gpix0 + p) * C + c8);
    *(uint4*)&As[p * 128 + (c8 ^ ((p & 7) << 3))] = v;
  }
  #pragma unroll
  for (int i = 0; i < 8; ++i)
    ((uint4*)Ws)[i * 256 + t] = ((const uint4*)Pm)[i * 256 + t];
  __syncthreads();

  const int wave = t >> 6, lane = t & 63;
  const int wr = wave >> 1, wc = wave & 1;
  const int rsel = lane & 15, quad = lane >> 4;

  f32x4 acc[4][4];
  #pragma unroll
  for (int mi = 0; mi < 4; ++mi)
    #pragma unroll
    for (int ni = 0; ni < 4; ++ni) acc[mi][ni] = (f32x4){0.f, 0.f, 0.f, 0.f};

  #pragma unroll
  for (int ks = 0; ks < 4; ++ks) {
    const int koff = ks * 32 + quad * 8;
    short8 afr[4], bfr[4];
    #pragma unroll
    for (int mi = 0; mi < 4; ++mi) {
      int r = wr * 64 + mi * 16 + rsel;
      afr[mi] = *(const short8*)&Ws[r * 128 + (koff ^ ((r & 7) << 3))];
    }
    #pragma unroll
    for (int ni = 0; ni < 4; ++ni) {
      int r = wc * 64 + ni * 16 + rsel;
      bfr[ni] = *(const short8*)&As[r * 128 + (koff ^ ((r & 7) << 3))];
    }
    #pragma unroll
    for (int mi = 0; mi < 4; ++mi)
      #pragma unroll
      for (int ni = 0; ni < 4; ++ni)
        acc[mi][ni] = __builtin_amdgcn_mfma_f32_16x16x32_bf16(afr[mi], bfr[ni], acc[mi][ni], 0, 0, 0);
  }

  __syncthreads();   // As MFMA reads done; re-stage As with the x~ tile
  #pragma unroll
  for (int i = 0; i < 8; ++i) {
    int linear = i * 256 + t;
    int c8 = (linear & 15) * 8;
    int p = linear >> 4;
    uint4 v = *(const uint4*)(xqh + (size_t)(gpix0 + p) * C + c8);
    *(uint4*)&As[p * 128 + (c8 ^ ((p & 7) << 3))] = v;
  }
  __syncthreads();

  #pragma unroll
  for (int mi = 0; mi < 4; ++mi)
    #pragma unroll
    for (int ni = 0; ni < 4; ++ni)
      #pragma unroll
      for (int r = 0; r < 4; ++r) {
        int och = wr * 64 + mi * 16 + quad * 4 + r;
        int pixl = wc * 64 + ni * 16 + rsel;
        float xr = bf2f(As[pixl * 128 + (och ^ ((pixl & 7) << 3))]);
        size_t addr = ((size_t)b * C + och) * HW + hw0 + pixl;
        out[addr] = xr + acc[mi][ni][r];
      }
}

extern "C" void kernel_launch(void* const* d_in, const int* in_sizes, int n_in,
                              void* d_out, int out_size, void* d_ws, size_t ws_size,
                              hipStream_t stream) {
  const float* x      = (const float*)d_in[0];
  const int*   psf    = (const int*)d_in[1];
  const float* delta  = (const float*)d_in[2];
  const float* w_qkv  = (const float*)d_in[3];
  const float* w_proj = (const float*)d_in[4];
  float* out = (float*)d_out;

  const size_t N = (size_t)4 * HW * C;                 // 8388608 elems
  unsigned short* qb = (unsigned short*)d_ws;          // 16 MB bf16 q' [pix][ch]
  unsigned short* xq = qb + N;                         // 16 MB bf16 x~ [pix][ch]
  unsigned short* ao = xq + N;                         // 16 MB bf16 out-acc
  unsigned short* Mt = ao + N;                         // 32 KB bf16 swz
  unsigned short* Pm = Mt + 16384;                     // 32 KB bf16 swz
  float* pw = (float*)(Pm + 16384);                    // 32 floats (pi follows)
  int*   pi = (int*)(pw + 32);                         // 16 ints

  k_prep<<<dim3(257), 128, 0, stream>>>(w_qkv, w_proj, delta, Mt, Pm, pw, pi);
  k_qx<<<dim3(512), 256, 0, stream>>>(x, Mt, qb, (unsigned*)xq);
  k_attn<<<dim3(HW), 256, 0, stream>>>(qb, (const unsigned*)xq, psf, (const int*)pw, pi, ao);
  k_proj<<<dim3(512), 256, 0, stream>>>(ao, Pm, xq, out);
}

// Round 6
// 147.958 us; speedup vs baseline: 1.1020x; 1.0418x over previous
//
#include <hip/hip_runtime.h>

#define HW 16384
#define C 128

typedef __attribute__((ext_vector_type(8))) short short8;
typedef __attribute__((ext_vector_type(4))) float f32x4;
typedef __attribute__((ext_vector_type(2))) float f32x2;
typedef __attribute__((ext_vector_type(16))) int v16i;

__device__ __forceinline__ unsigned short f2bf(float f) {
  union { float f; unsigned u; } v; v.f = f;
  return (unsigned short)((v.u + 0x7fffu + ((v.u >> 16) & 1u)) >> 16);
}
#if __has_builtin(__builtin_amdgcn_cvt_pk_bf16_f32)
typedef __attribute__((ext_vector_type(2))) __bf16 bf16x2;
__device__ __forceinline__ unsigned pk2(float a, float b) {   // HW RNE pack
  union { bf16x2 v; unsigned u; } cv;
  cv.v = __builtin_amdgcn_cvt_pk_bf16_f32(a, b);
  return cv.u;
}
#else
__device__ __forceinline__ unsigned pk2(float a, float b) {   // SW RNE pack
  return (unsigned)f2bf(a) | ((unsigned)f2bf(b) << 16);
}
#endif
__device__ __forceinline__ unsigned short f2bf1(float a) {
  return (unsigned short)(pk2(a, a) & 0xffffu);
}
__device__ __forceinline__ float bflo(unsigned w) {
  union { unsigned u; float f; } v; v.u = w << 16; return v.f;
}
__device__ __forceinline__ float bfhi(unsigned w) {
  union { unsigned u; float f; } v; v.u = w & 0xffff0000u; return v.f;
}
__device__ __forceinline__ float asf(int u) {
  union { int u; float f; } v; v.u = u; return v.f;
}
__device__ __forceinline__ float bf2f(unsigned short h) {
  union { unsigned u; float f; } v; v.u = ((unsigned)h) << 16; return v.f;
}

// ---------------- Kernel 0: precompute Mt = C^-0.5 * Wk^T Wq, P = Wproj @ Wv,
// both stored bf16 with the LDS XOR swizzle pre-applied, plus bilinear pw/pi.
__global__ __launch_bounds__(128) void k_prep(const float* __restrict__ w_qkv,
                                              const float* __restrict__ w_proj,
                                              const float* __restrict__ delta,
                                              unsigned short* __restrict__ Mt,
                                              unsigned short* __restrict__ Pm,
                                              float* __restrict__ pw,
                                              int* __restrict__ pi) {
  const int bid = blockIdx.x;
  const int t = threadIdx.x;
  if (bid == 256) {
    if (t < 8) {
      float s0 = tanhf(delta[t * 2 + 0]) * 4.0f;  // col shift (x)
      float s1 = tanhf(delta[t * 2 + 1]) * 4.0f;  // row shift (y)
      float f0 = floorf(s0), f1 = floorf(s1);
      pi[2 * t + 0] = (int)f0;
      pi[2 * t + 1] = (int)f1;
      float fx = s0 - f0, fy = s1 - f1;
      pw[4 * t + 0] = (1.0f - fx) * (1.0f - fy);
      pw[4 * t + 1] = fx * (1.0f - fy);
      pw[4 * t + 2] = (1.0f - fx) * fy;
      pw[4 * t + 3] = fx * fy;
    }
    return;
  }
  const int R = bid & 127;
  float acc = 0.0f;
  if (bid < 128) {                         // Mt row R
    const float* wq = w_qkv;               // Wq[j][c]
    const float* wk = w_qkv + 128 * 128;   // Wk[j][o]
    #pragma unroll 16
    for (int j = 0; j < 128; ++j)
      acc += wk[j * 128 + R] * wq[j * 128 + t];   // wk: scalar, wq: coalesced
    acc *= 0.08838834764831845f;           // fold C^-0.5 into the logits
    Mt[R * 128 + (t ^ ((R & 7) << 3))] = f2bf1(acc);
  } else {                                 // P row R
    const float* wv = w_qkv + 2 * 128 * 128;  // Wv[j][c]
    const float* wp = w_proj + (size_t)R * 128;  // Wproj[R][j]
    #pragma unroll 16
    for (int j = 0; j < 128; ++j)
      acc += wp[j] * wv[j * 128 + t];
    Pm[R * 128 + (t ^ ((R & 7) << 3))] = f2bf1(acc);
  }
}

// ---------------- Kernel 1: q' = x * Mt GEMM + bf16 transposed copy of x -----
// 128-pixel tiles, Ws staged in LDS. q' repacked through the freed Xs buffer
// so qb stores are coalesced uint4 (not 2B scatter).  (R4-verified.)
__global__ __launch_bounds__(256) void k_qx(const float* __restrict__ x,
                                            const unsigned short* __restrict__ Mt,
                                            unsigned short* __restrict__ qb,
                                            unsigned* __restrict__ xq) {
  __shared__ __align__(16) unsigned char smem[65536];
  unsigned short* Xs = (unsigned short*)smem;            // [pix][k] 32 KB
  unsigned short* Ws = (unsigned short*)(smem + 32768);  // [och][k] 32 KB
  const int t = threadIdx.x;
  const int gpix0 = blockIdx.x * 128;
  const int b = gpix0 >> 14;
  const int hw0 = gpix0 & (HW - 1);

  // stage Xs [pix][k] bf16, xor-swizzled
  const float* xb = x + (size_t)b * C * HW + hw0;
  #pragma unroll
  for (int i = 0; i < 16; ++i) {
    int linear = i * 256 + t;
    int p = linear & 127;
    int c4 = (linear >> 7) * 4;
    float a0 = xb[(size_t)(c4 + 0) * HW + p];
    float a1 = xb[(size_t)(c4 + 1) * HW + p];
    float a2 = xb[(size_t)(c4 + 2) * HW + p];
    float a3 = xb[(size_t)(c4 + 3) * HW + p];
    int cc = c4 ^ ((p & 7) << 3);
    *(uint2*)&Xs[p * 128 + cc] = make_uint2(pk2(a0, a1), pk2(a2, a3));
  }
  // stage Ws: pre-swizzled bf16 Mt, straight 32 KB copy
  #pragma unroll
  for (int i = 0; i < 8; ++i)
    ((uint4*)Ws)[i * 256 + t] = ((const uint4*)Mt)[i * 256 + t];
  __syncthreads();

  // coalesced xq emit from staged Xs: [pix][64 dwords]
  #pragma unroll
  for (int i = 0; i < 8; ++i) {
    int linear = i * 256 + t;
    int c8 = (linear & 15) * 8;
    int prow = linear >> 4;
    uint4 v = *(const uint4*)&Xs[prow * 128 + (c8 ^ ((prow & 7) << 3))];
    *(uint4*)&xq[((size_t)(gpix0 + prow)) * 64 + (c8 >> 1)] = v;
  }

  const int wave = t >> 6, lane = t & 63;
  const int wr = wave >> 1, wc = wave & 1;
  const int rsel = lane & 15, quad = lane >> 4;

  f32x4 acc[4][4];
  #pragma unroll
  for (int mi = 0; mi < 4; ++mi)
    #pragma unroll
    for (int ni = 0; ni < 4; ++ni) acc[mi][ni] = (f32x4){0.f, 0.f, 0.f, 0.f};
  #pragma unroll
  for (int ks = 0; ks < 4; ++ks) {
    const int koff = ks * 32 + quad * 8;
    short8 afr[4], bfr[4];
    #pragma unroll
    for (int mi = 0; mi < 4; ++mi) {
      int r = wr * 64 + mi * 16 + rsel;
      afr[mi] = *(const short8*)&Xs[r * 128 + (koff ^ ((r & 7) << 3))];
    }
    #pragma unroll
    for (int ni = 0; ni < 4; ++ni) {
      int r = wc * 64 + ni * 16 + rsel;
      bfr[ni] = *(const short8*)&Ws[r * 128 + (koff ^ ((r & 7) << 3))];
    }
    #pragma unroll
    for (int mi = 0; mi < 4; ++mi)
      #pragma unroll
      for (int ni = 0; ni < 4; ++ni)
        acc[mi][ni] = __builtin_amdgcn_mfma_f32_16x16x32_bf16(afr[mi], bfr[ni], acc[mi][ni], 0, 0, 0);
  }
  __syncthreads();   // all Xs/Ws reads done; reuse Xs as q'-tile
  #pragma unroll
  for (int mi = 0; mi < 4; ++mi)
    #pragma unroll
    for (int ni = 0; ni < 4; ++ni)
      #pragma unroll
      for (int r = 0; r < 4; ++r) {
        int p = wr * 64 + mi * 16 + quad * 4 + r;
        int ch = wc * 64 + ni * 16 + rsel;
        Xs[p * 128 + (ch ^ ((p & 7) << 3))] = f2bf1(acc[mi][ni][r]);
      }
  __syncthreads();
  // coalesced qb store
  #pragma unroll
  for (int i = 0; i < 8; ++i) {
    int linear = i * 256 + t;
    int c8 = (linear & 15) * 8;
    int prow = linear >> 4;
    uint4 v = *(const uint4*)&Xs[prow * 128 + (c8 ^ ((prow & 7) << 3))];
    *(uint4*)(qb + (size_t)(gpix0 + prow) * C + c8) = v;
  }
}

// ---------------- Kernel 2: fused gather + attention (bf16, 2 pix/wave) ------
// Lanes 0-31 = pixel A, 32-63 = pixel B; each lane owns 4 channels (uint2).
// Per corner one dwordx2 load serves a whole pixel per half. Reduce = 5 shfl
// rounds shared by both pixels; softmax/out pass runs wave-wide for both.
__global__ __launch_bounds__(256) void k_attn(const unsigned short* __restrict__ qb,
                                              const unsigned* __restrict__ xq,
                                              const int* __restrict__ psf,
                                              const int* __restrict__ pwu,
                                              unsigned short* __restrict__ ao) {
  const int t = threadIdx.x;
  const int li = t & 31;
  const int half = (t >> 5) & 1;
  const int gid = blockIdx.x;
  const int b = gid & 3;                         // batch -> XCD spread
  const int grp = gid >> 2;
  const int pixl = (grp << 3) + ((t >> 6) << 1) + half;   // per-lane pixel
  const size_t spix = ((size_t)b << 14) + pixl;

  // scalar tables: pw[0..15], pw[16..31], pi[0..15] (contiguous in workspace)
  v16i w0, w1, tpi;
  asm volatile(
      "s_load_dwordx16 %0, %3, 0\n\t"
      "s_load_dwordx16 %1, %3, 64\n\t"
      "s_load_dwordx16 %2, %3, 128\n\t"
      "s_waitcnt lgkmcnt(0)"
      : "=&s"(w0), "=&s"(w1), "=&s"(tpi)
      : "s"(pwu));

  // per-lane anchor row (uniform within each 32-lane half -> broadcast)
  const int4* pr = (const int4*)(psf + spix * 16);
  int4 a0 = pr[0], a1 = pr[1], a2 = pr[2], a3 = pr[3];
  int va[16] = {a0.x, a0.y, a0.z, a0.w, a1.x, a1.y, a1.z, a1.w,
                a2.x, a2.y, a2.z, a2.w, a3.x, a3.y, a3.z, a3.w};

  // q for my 4 channels
  const uint2 qp = *(const uint2*)((const unsigned*)qb + spix * 64 + 2 * li);
  const float q0 = bflo(qp.x), q1 = bfhi(qp.x);
  const float q2 = bflo(qp.y), q3 = bfhi(qp.y);

  const unsigned* xB = xq + (((size_t)b << 14) << 6);  // batch base (dwords)

  float s0[8], s1[8], s2[8], s3[8], dk[8];
  #pragma unroll
  for (int k = 0; k < 8; ++k) {
    const int x0 = va[2 * k + 0] + tpi[2 * k + 0];
    const int y0 = va[2 * k + 1] + tpi[2 * k + 1];
    float t0 = 0.f, t1 = 0.f, t2 = 0.f, t3 = 0.f;
    #pragma unroll
    for (int cn = 0; cn < 4; ++cn) {
      const int xi = x0 + (cn & 1);
      const int yi = y0 + (cn >> 1);
      const bool valid = ((unsigned)xi <= 127u) & ((unsigned)yi <= 127u);
      const int xc = min(max(xi, 0), 127);   // v_med3_i32
      const int yc = min(max(yi, 0), 127);
      const int widx = k * 4 + cn;
      const float wv = valid ? asf(widx < 16 ? w0[widx & 15] : w1[widx & 15]) : 0.0f;
      const uint2 w2 = *(const uint2*)&xB[((size_t)((yc << 7) + xc) << 6) + 2 * li];
      t0 = fmaf(bflo(w2.x), wv, t0); t1 = fmaf(bfhi(w2.x), wv, t1);
      t2 = fmaf(bflo(w2.y), wv, t2); t3 = fmaf(bfhi(w2.y), wv, t3);
    }
    s0[k] = t0; s1[k] = t1; s2[k] = t2; s3[k] = t3;
    dk[k] = fmaf(q0, t0, fmaf(q1, t1, fmaf(q2, t2, q3 * t3)));
  }
  #pragma unroll
  for (int off = 16; off > 0; off >>= 1) {
    #pragma unroll
    for (int k = 0; k < 8; ++k) dk[k] += __shfl_xor(dk[k], off);
  }
  float m = dk[0];
  #pragma unroll
  for (int k = 1; k < 8; ++k) m = fmaxf(m, dk[k]);
  float den = 0.0f;
  #pragma unroll
  for (int k = 0; k < 8; ++k) { dk[k] = __expf(dk[k] - m); den += dk[k]; }
  const float inv = 1.0f / den;
  float o0 = 0.f, o1 = 0.f, o2 = 0.f, o3 = 0.f;
  #pragma unroll
  for (int k = 0; k < 8; ++k) {
    const float pk = dk[k] * inv;
    o0 = fmaf(pk, s0[k], o0); o1 = fmaf(pk, s1[k], o1);
    o2 = fmaf(pk, s2[k], o2); o3 = fmaf(pk, s3[k], o3);
  }
  *(uint2*)((unsigned*)ao + spix * 64 + 2 * li) = make_uint2(pk2(o0, o1), pk2(o2, o3));
}

// ---------------- Kernel 3: out = bf16(x) + P @ ao  (128-tile, Ws in LDS) ----
// Residual read from the 16MB bf16 xq copy (re-staged through the freed As
// buffer after MFMA) instead of the 32MB fp32 x.  (R4-verified.)
__global__ __launch_bounds__(256) void k_proj(const unsigned short* __restrict__ ao,
                                              const unsigned short* __restrict__ Pm,
                                              const unsigned short* __restrict__ xqh,
                                              float* __restrict__ out) {
  __shared__ __align__(16) unsigned short As[128 * 128];
  __shared__ __align__(16) unsigned short Ws[128 * 128];
  const int t = threadIdx.x;
  const int gpix0 = blockIdx.x * 128;
  const int b = gpix0 >> 14;
  const int hw0 = gpix0 & (HW - 1);

  #pragma unroll
  for (int i = 0; i < 8; ++i) {
    int linear = i * 256 + t;
    int c8 = (linear & 15) * 8;
    int p = linear >> 4;
    uint4 v = *(const uint4*)(ao + (size_t)(gpix0 + p) * C + c8);
    *(uint4*)&As[p * 128 + (c8 ^ ((p & 7) << 3))] = v;
  }
  #pragma unroll
  for (int i = 0; i < 8; ++i)
    ((uint4*)Ws)[i * 256 + t] = ((const uint4*)Pm)[i * 256 + t];
  __syncthreads();

  const int wave = t >> 6, lane = t & 63;
  const int wr = wave >> 1, wc = wave & 1;
  const int rsel = lane & 15, quad = lane >> 4;

  f32x4 acc[4][4];
  #pragma unroll
  for (int mi = 0; mi < 4; ++mi)
    #pragma unroll
    for (int ni = 0; ni < 4; ++ni) acc[mi][ni] = (f32x4){0.f, 0.f, 0.f, 0.f};

  #pragma unroll
  for (int ks = 0; ks < 4; ++ks) {
    const int koff = ks * 32 + quad * 8;
    short8 afr[4], bfr[4];
    #pragma unroll
    for (int mi = 0; mi < 4; ++mi) {
      int r = wr * 64 + mi * 16 + rsel;
      afr[mi] = *(const short8*)&Ws[r * 128 + (koff ^ ((r & 7) << 3))];
    }
    #pragma unroll
    for (int ni = 0; ni < 4; ++ni) {
      int r = wc * 64 + ni * 16 + rsel;
      bfr[ni] = *(const short8*)&As[r * 128 + (koff ^ ((r & 7) << 3))];
    }
    #pragma unroll
    for (int mi = 0; mi < 4; ++mi)
      #pragma unroll
      for (int ni = 0; ni < 4; ++ni)
        acc[mi][ni] = __builtin_amdgcn_mfma_f32_16x16x32_bf16(afr[mi], bfr[ni], acc[mi][ni], 0, 0, 0);
  }

  __syncthreads();   // As MFMA reads done; re-stage As with the x~ tile
  #pragma unroll
  for (int i = 0; i < 8; ++i) {
    int linear = i * 256 + t;
    int c8 = (linear & 15) * 8;
    int p = linear >> 4;
    uint4 v = *(const uint4*)(xqh + (size_t)(gpix0 + p) * C + c8);
    *(uint4*)&As[p * 128 + (c8 ^ ((p & 7) << 3))] = v;
  }
  __syncthreads();

  #pragma unroll
  for (int mi = 0; mi < 4; ++mi)
    #pragma unroll
    for (int ni = 0; ni < 4; ++ni)
      #pragma unroll
      for (int r = 0; r < 4; ++r) {
        int och = wr * 64 + mi * 16 + quad * 4 + r;
        int pixl = wc * 64 + ni * 16 + rsel;
        float xr = bf2f(As[pixl * 128 + (och ^ ((pixl & 7) << 3))]);
        size_t addr = ((size_t)b * C + och) * HW + hw0 + pixl;
        out[addr] = xr + acc[mi][ni][r];
      }
}

extern "C" void kernel_launch(void* const* d_in, const int* in_sizes, int n_in,
                              void* d_out, int out_size, void* d_ws, size_t ws_size,
                              hipStream_t stream) {
  const float* x      = (const float*)d_in[0];
  const int*   psf    = (const int*)d_in[1];
  const float* delta  = (const float*)d_in[2];
  const float* w_qkv  = (const float*)d_in[3];
  const float* w_proj = (const float*)d_in[4];
  float* out = (float*)d_out;

  const size_t N = (size_t)4 * HW * C;                 // 8388608 elems
  unsigned short* qb = (unsigned short*)d_ws;          // 16 MB bf16 q' [pix][ch]
  unsigned short* xq = qb + N;                         // 16 MB bf16 x~ [pix][ch]
  unsigned short* ao = xq + N;                         // 16 MB bf16 out-acc
  unsigned short* Mt = ao + N;                         // 32 KB bf16 swz
  unsigned short* Pm = Mt + 16384;                     // 32 KB bf16 swz
  float* pw = (float*)(Pm + 16384);                    // 32 floats (pi follows)
  int*   pi = (int*)(pw + 32);                         // 16 ints
  (void)pi;

  k_prep<<<dim3(257), 128, 0, stream>>>(w_qkv, w_proj, delta, Mt, Pm, pw, pi);
  k_qx<<<dim3(512), 256, 0, stream>>>(x, Mt, qb, (unsigned*)xq);
  k_attn<<<dim3(8192), 256, 0, stream>>>(qb, (const unsigned*)xq, psf, (const int*)pw, ao);
  k_proj<<<dim3(512), 256, 0, stream>>>(ao, Pm, xq, out);
}